// Round 11
// baseline (9905.339 us; speedup 1.0000x reference)
//
#include <hip/hip_runtime.h>
#include <hip/hip_fp16.h>

#define GD 256   // 256 WGs for setup; recurrence uses w<128 (16 groups x 8)
#define BD 1024  // 16 waves

constexpr int TSTEPS = 256;
constexpr int DD = 512;
constexpr int LC = 128;

// ---- ws float offsets ----
constexpr size_t OFF_FLAGS_F = 0;       // grid flags: 256 lines (stride 32 ints)
constexpr size_t OFF_REL_F   = 8192;    // 8 release lines
constexpr size_t OFF_SCF     = 8448;    // score flags [16 g][8 oct][32 ints]
constexpr size_t OFF_HF      = 12544;   // h flags     [16 g][8 oct][32 ints]
constexpr size_t OFF_SCP     = 16640;   // [2 par][32 b][8 oct][128 l] f32
constexpr size_t OFF_H16_F   = 82176;   // h16 base
// ---- h16-unit offsets ----
constexpr size_t HO_HX    = 0;          // [2 par][32 b][512] h
constexpr size_t HO_ATT   = 32768;      // [4096 r][512] attc
constexpr size_t HO_U16   = 2129920;    // [8 oct][256 kp][256 cc] h2
constexpr size_t HO_WH16  = 3178496;    // [8 octa][256 kp][64 a] h2
constexpr size_t HO_CTXV  = 3440640;    // [32 b][8 oct][128 l][256 cc]
constexpr size_t HO_XW    = 11829248;   // [32 b][8 oct][256 st][256 cc]

typedef _Float16 h16;
typedef _Float16 h2  __attribute__((ext_vector_type(2)));
typedef _Float16 h8v __attribute__((ext_vector_type(8)));
union H8  { h8v v; h2 p[4]; };
union H2U { h2 h; unsigned u; };
union HSU { h16 h; unsigned short u; };

__device__ __forceinline__ float rcp_fast(float x) { return __builtin_amdgcn_rcpf(x); }
__device__ __forceinline__ float ftanh(float x) {
  float e = __expf(2.0f * x);
  return 1.0f - 2.0f * rcp_fast(e + 1.0f);
}
__device__ __forceinline__ float fsig(float x) { return rcp_fast(1.0f + __expf(-x)); }
__device__ __forceinline__ float fdot2(h2 a, h2 b, float c) {
  return __builtin_amdgcn_fdot2(a, b, c, false);
}

__device__ __forceinline__ float cloadf(const float* p) {
  return __hip_atomic_load(p, __ATOMIC_RELAXED, __HIP_MEMORY_SCOPE_AGENT);
}
__device__ __forceinline__ unsigned cloadu(const unsigned* p) {
  return __hip_atomic_load(p, __ATOMIC_RELAXED, __HIP_MEMORY_SCOPE_AGENT);
}
__device__ __forceinline__ void cstoref(float* p, float v) {
  __hip_atomic_store(p, v, __ATOMIC_RELAXED, __HIP_MEMORY_SCOPE_AGENT);
}
__device__ __forceinline__ void cstorei(int* p, int v) {
  __hip_atomic_store(p, v, __ATOMIC_RELAXED, __HIP_MEMORY_SCOPE_AGENT);
}
__device__ __forceinline__ void cstoreu(unsigned* p, unsigned v) {
  __hip_atomic_store(p, v, __ATOMIC_RELAXED, __HIP_MEMORY_SCOPE_AGENT);
}
__device__ __forceinline__ void cstoreu8(unsigned long long* p, unsigned long long v) {
  __hip_atomic_store(p, v, __ATOMIC_RELAXED, __HIP_MEMORY_SCOPE_AGENT);
}
__device__ __forceinline__ void cstores(h16* p, h16 v) {
  HSU s; s.h = v;
  __hip_atomic_store((unsigned short*)p, s.u, __ATOMIC_RELAXED,
                     __HIP_MEMORY_SCOPE_AGENT);
}

// grid barrier (setup only)
__device__ __forceinline__ void gsync(int* flags, int* rel, int w, int& gen) {
  __syncthreads();
  gen++;
  const int t = threadIdx.x;
  if (w == 0) {
    if (t < 64) {
      if (t == 0)
        __hip_atomic_store(flags, gen, __ATOMIC_RELAXED, __HIP_MEMORY_SCOPE_AGENT);
      for (;;) {
        int m = gen;
#pragma unroll
        for (int i = 0; i < 4; i++) {
          int v = __hip_atomic_load(flags + (t + i * 64) * 32,
                                    __ATOMIC_RELAXED, __HIP_MEMORY_SCOPE_AGENT);
          m = (v < m) ? v : m;
        }
        if (__all(m >= gen)) break;
      }
      if (t == 0) {
#pragma unroll
        for (int i = 0; i < 8; i++)
          __hip_atomic_store(rel + i * 32, gen, __ATOMIC_RELAXED,
                             __HIP_MEMORY_SCOPE_AGENT);
      }
    }
    asm volatile("" ::: "memory");
  } else {
    if (t == 0) {
      __hip_atomic_store(flags + w * 32, gen, __ATOMIC_RELAXED,
                         __HIP_MEMORY_SCOPE_AGENT);
      const int* r = rel + (w & 7) * 32;
      while (__hip_atomic_load(r, __ATOMIC_RELAXED, __HIP_MEMORY_SCOPE_AGENT) < gen)
        __builtin_amdgcn_s_sleep(1);
    }
    asm volatile("" ::: "memory");
  }
  __syncthreads();
}

// poll 8 per-WG monotonic flags (stride-32 lines) until all >= tgt
__device__ __forceinline__ void pollgrp(const int* f8, int tgt) {
  const int t = threadIdx.x;
  if (t < 64) {
    for (;;) {
      int v = tgt;
      if (t < 8)
        v = __hip_atomic_load(f8 + t * 32, __ATOMIC_RELAXED,
                              __HIP_MEMORY_SCOPE_AGENT);
      if (__all(v >= tgt)) break;
      __builtin_amdgcn_s_sleep(1);
    }
  }
  asm volatile("" ::: "memory");
  __syncthreads();
}

__global__ __launch_bounds__(BD) void attn_lstm_persistent(
    const float* __restrict__ x, const float* __restrict__ ctx,
    const float* __restrict__ W, const float* __restrict__ V,
    const float* __restrict__ U, const float* __restrict__ bias,
    const float* __restrict__ Wh, const float* __restrict__ Wc,
    const float* __restrict__ batt, const float* __restrict__ wprj,
    float* __restrict__ out, float* __restrict__ ws) {
  __shared__ __align__(16) unsigned char smem[65280];
  h16*   attcL = (h16*)smem;                   // [2 bq][128 l][66] = 33792 B
  float* red   = (float*)(smem + 33792);       // 4096 f (hU 0..2047, hatt 2048..4095; PV 0..4095)
  h2*    hLDS  = (h2*)(smem + 50176);          // [2 bq][256 kp]
  float* spp   = (float*)(smem + 52224);       // [2 bq][1024]
  float* sl    = (float*)(smem + 60416);       // [2 bq][128]; phase-A alias: hattL[2][64]
  h2*    anL   = (h2*)(smem + 61440);          // [2 bq][64] fp16 alpha pairs
  float* wpL   = (float*)(smem + 61952);       // 64
  float* biasS = (float*)(smem + 62208);       // 256
  float* pre   = (float*)(smem + 63232);       // [2 bq][256]; also holds hU sums from A

  const int w = blockIdx.x;
  const int t = threadIdx.x;

  int* flags = (int*)(ws + OFF_FLAGS_F);
  int* rel   = (int*)(ws + OFF_REL_F);
  float* scP = ws + OFF_SCP;
  h16* hb16  = (h16*)(ws + OFF_H16_F);
  h16* hX    = hb16 + HO_HX;
  h16* att16 = hb16 + HO_ATT;
  h16* ctxVp = hb16 + HO_CTXV;
  h16* xw16  = hb16 + HO_XW;

  int gen = 0;

  // ================= setup (all 256 WGs; verified packing) =================
  {
    const int kp = w;
    {
      const float* r0p = U + (size_t)(2 * kp) * 2048;
      const float* r1p = r0p + 2048;
      const int col0 = 2 * t;
      float u00 = r0p[col0], u01 = r0p[col0 + 1];
      float u10 = r1p[col0], u11 = r1p[col0 + 1];
      int oc  = (col0 & 511) >> 6;
      int cc0 = ((col0 >> 9) << 6) | (col0 & 63);
      H2U p0; p0.h = h2{(h16)u00, (h16)u10};
      H2U p1; p1.h = h2{(h16)u01, (h16)u11};
      unsigned long long pk =
          (unsigned long long)p0.u | ((unsigned long long)p1.u << 32);
      cstoreu8((unsigned long long*)((h2*)(hb16 + HO_U16) +
                                     (size_t)oc * 65536 + (size_t)kp * 256 + cc0),
               pk);
    }
    if (t < 512) {
      float w0 = Wh[(size_t)(2 * kp) * DD + t];
      float w1 = Wh[(size_t)(2 * kp + 1) * DD + t];
      H2U pu; pu.h = h2{(h16)w0, (h16)w1};
      cstoreu((unsigned*)((h2*)(hb16 + HO_WH16) + (size_t)(t >> 6) * 16384 +
                          (size_t)kp * 64 + (t & 63)),
              pu.u);
    }
  }
  // attc16 = fp16(ctx @ Wc + b_att): 16 rows per WG
  {
    float* fbuf = (float*)smem;  // 32 KB staging
    const int r0 = w * 16;
#pragma unroll
    for (int i = 0; i < 2; i++) {
      int idx4 = i * BD + t;
      int row = idx4 >> 7, c4 = idx4 & 127;
      ((float4*)fbuf)[idx4] = ((const float4*)(ctx + (size_t)(r0 + row) * DD))[c4];
    }
    __syncthreads();
    const int a0 = t & 511, rh = t >> 9;
    float acc[8];
#pragma unroll
    for (int r = 0; r < 8; r++) acc[r] = 0.f;
    for (int cc = 0; cc < DD; cc++) {
      float wv = Wc[(size_t)cc * DD + a0];
#pragma unroll
      for (int r = 0; r < 8; r++)
        acc[r] += fbuf[(8 * rh + r) * DD + cc] * wv;
    }
    const float ba = batt[a0];
    for (int r = 0; r < 8; r++)
      cstores(att16 + (size_t)(r0 + 8 * rh + r) * DD + a0, (h16)(acc[r] + ba));
    __syncthreads();
  }
  // xw16 / ctxVp with setup-role (bS = w>>3, octS = w&7)
  {
    const int bS = w >> 3, octS = w & 7;
    h2* xstage = (h2*)smem;  // [32][256]
    for (int chk = 0; chk < 8; chk++) {
      const int st0 = chk * 32;
      {
        const int row = t >> 5, seg = t & 31;
        const float* src = x + ((size_t)bS * TSTEPS + st0 + row) * DD + seg * 16;
        h2* dst = xstage + row * 256 + seg * 8;
#pragma unroll
        for (int q = 0; q < 4; q++) {
          float4 v = *(const float4*)(src + 4 * q);
          dst[2 * q]     = h2{(h16)v.x, (h16)v.y};
          dst[2 * q + 1] = h2{(h16)v.z, (h16)v.w};
        }
      }
      __syncthreads();
      const int cc = t & 255, sq = t >> 8;
      const int col = ((cc >> 6) << 9) + 64 * octS + (cc & 63);
      float acc[8];
#pragma unroll
      for (int jj = 0; jj < 8; jj++) acc[jj] = 0.f;
#pragma unroll 2
      for (int kp = 0; kp < 256; kp++) {
        float w0 = W[(size_t)(2 * kp) * 2048 + col];
        float w1 = W[(size_t)(2 * kp + 1) * 2048 + col];
        h2 wp = h2{(h16)w0, (h16)w1};
#pragma unroll
        for (int jj = 0; jj < 8; jj++)
          acc[jj] = fdot2(xstage[(sq * 8 + jj) * 256 + kp], wp, acc[jj]);
      }
#pragma unroll
      for (int jj = 0; jj < 8; jj++)
        cstores(xw16 + (((size_t)(bS * 8 + octS) * 256) + st0 + sq * 8 + jj) * 256 + cc,
                (h16)acc[jj]);
      __syncthreads();
    }
    for (int chk = 0; chk < 4; chk++) {
      const int l0 = chk * 32;
      {
        const int row = t >> 5, seg = t & 31;
        const float* src = ctx + ((size_t)bS * LC + l0 + row) * DD + seg * 16;
        h2* dst = xstage + row * 256 + seg * 8;
#pragma unroll
        for (int q = 0; q < 4; q++) {
          float4 v = *(const float4*)(src + 4 * q);
          dst[2 * q]     = h2{(h16)v.x, (h16)v.y};
          dst[2 * q + 1] = h2{(h16)v.z, (h16)v.w};
        }
      }
      __syncthreads();
      const int cc = t & 255, lq2 = t >> 8;
      const int col = ((cc >> 6) << 9) + 64 * octS + (cc & 63);
      float acc[8];
#pragma unroll
      for (int jj = 0; jj < 8; jj++) acc[jj] = 0.f;
#pragma unroll 2
      for (int kp = 0; kp < 256; kp++) {
        float v0 = V[(size_t)(2 * kp) * 2048 + col];
        float v1 = V[(size_t)(2 * kp + 1) * 2048 + col];
        h2 vp = h2{(h16)v0, (h16)v1};
#pragma unroll
        for (int jj = 0; jj < 8; jj++)
          acc[jj] = fdot2(xstage[(lq2 * 8 + jj) * 256 + kp], vp, acc[jj]);
      }
#pragma unroll
      for (int jj = 0; jj < 8; jj++)
        cstores(ctxVp + (((size_t)(bS * 8 + octS) * 128) + l0 + lq2 * 8 + jj) * 256 + cc,
                (h16)acc[jj]);
      __syncthreads();
    }
  }
  gsync(flags, rel, w, gen);
  if (w >= 128) return;   // recurrence: 128 WGs = 16 groups x 8

  // recurrence roles
  const int g = w >> 3, oct = w & 7;
  const int b0 = 2 * g, b1 = 2 * g + 1;
  int* scF = (int*)(ws + OFF_SCF) + g * 256;   // group's 8 score-flag lines
  int* hF  = (int*)(ws + OFF_HF) + g * 256;    // group's 8 h-flag lines
  int* scFmine = scF + oct * 32;
  int* hFmine  = hF + oct * 32;
  float* hattL = sl;                            // phase-A alias [2][64]

  const h2* U2  = (const h2*)(hb16 + HO_U16) + (size_t)oct * 65536;
  const h2* WhB = (const h2*)(hb16 + HO_WH16) + (size_t)oct * 16384;

  float c_reg = 0.f;     // t<128: c[b0+ (t>>6)][64*oct + (t&63)]
  float hn_prev = 0.f;

  // persistent: ctxV both batches in regs (32 VGPR)
  const int ccg = t & 31, lq = t >> 5;
  h2 cvA01[8], cvA23[8], cvB01[8], cvB23[8];
  {
    const h16* cvb = ctxVp + ((size_t)(b0 * 8 + oct) * 128) * 256 + ccg * 8;
    H8 p0, p1, p2, p3;
    p0.v = *(const h8v*)(cvb + (size_t)(4 * lq + 0) * 256);
    p1.v = *(const h8v*)(cvb + (size_t)(4 * lq + 1) * 256);
    p2.v = *(const h8v*)(cvb + (size_t)(4 * lq + 2) * 256);
    p3.v = *(const h8v*)(cvb + (size_t)(4 * lq + 3) * 256);
#pragma unroll
    for (int j8 = 0; j8 < 8; j8++) {
      cvA01[j8] = h2{p0.v[j8], p1.v[j8]};
      cvA23[j8] = h2{p2.v[j8], p3.v[j8]};
    }
    const h16* cvb1 = ctxVp + ((size_t)(b1 * 8 + oct) * 128) * 256 + ccg * 8;
    p0.v = *(const h8v*)(cvb1 + (size_t)(4 * lq + 0) * 256);
    p1.v = *(const h8v*)(cvb1 + (size_t)(4 * lq + 1) * 256);
    p2.v = *(const h8v*)(cvb1 + (size_t)(4 * lq + 2) * 256);
    p3.v = *(const h8v*)(cvb1 + (size_t)(4 * lq + 3) * 256);
#pragma unroll
    for (int j8 = 0; j8 < 8; j8++) {
      cvB01[j8] = h2{p0.v[j8], p1.v[j8]};
      cvB23[j8] = h2{p2.v[j8], p3.v[j8]};
    }
  }
  // attcL: both batches' 64 a-cols
  {
    const int l = t >> 3, as = t & 7;
#pragma unroll
    for (int bq = 0; bq < 2; bq++) {
      uint4 v = *(const uint4*)(att16 + (size_t)((b0 + bq) * LC + l) * DD +
                                64 * oct + 8 * as);
      unsigned* dp = (unsigned*)(attcL + (size_t)(bq * 128 + l) * 66 + 8 * as);
      dp[0] = v.x; dp[1] = v.y; dp[2] = v.z; dp[3] = v.w;
    }
  }
  if (t < 64) wpL[t] = wprj[64 * oct + t];
  if (t < 256) biasS[t] = bias[(size_t)(t >> 6) * 512 + 64 * oct + (t & 63)];
  __syncthreads();

  // ========== recurrence: 2 batches pipelined, flag-sync, parity buffers ====
  for (int step = 0; step < TSTEPS; step++) {
    const int par = step & 1, parp = par ^ 1;
    float xwv0 = 0.f, xwv1 = 0.f;

    // deferred out stores (previous step)
    if (t < 128 && step > 0) {
      int bq = t >> 6, d = t & 63;
      out[((size_t)(b0 + bq) * TSTEPS + step - 1) * DD + 64 * oct + d] = hn_prev;
    }

    // ---- Phase A ----
    pollgrp(hF, step);        // h(step-1) published with flag value = step
    if (t < 512) {
      unsigned hv = 0;
      if (step > 0) {
        int bq = t >> 8, idx = t & 255;
        hv = cloadu((const unsigned*)(hX + ((size_t)parp * 32 + b0 + bq) * DD +
                                      2 * idx));
      }
      ((unsigned*)hLDS)[t] = hv;
    }
    __syncthreads();
    // hU both batches: one U stream
    {
      const int cc = t & 255, kq = t >> 8;
      const int base = 64 * kq;
      float f0 = 0.f, f1 = 0.f;
#pragma unroll
      for (int i = 0; i < 64; i++) {
        h2 uu = U2[(size_t)(base + i) * 256 + cc];
        f0 = fdot2(hLDS[base + i], uu, f0);
        f1 = fdot2(hLDS[256 + base + i], uu, f1);
      }
      red[(0 * 4 + kq) * 256 + cc] = f0;
      red[(1 * 4 + kq) * 256 + cc] = f1;
    }
    // hatt both batches: one Wh stream
    {
      const int aL = t & 63, ks = t >> 6;
      float g0 = 0.f, g1 = 0.f;
#pragma unroll
      for (int i = 0; i < 16; i++) {
        h2 ww = WhB[(size_t)(16 * ks + i) * 64 + aL];
        g0 = fdot2(hLDS[16 * ks + i], ww, g0);
        g1 = fdot2(hLDS[256 + 16 * ks + i], ww, g1);
      }
      red[2048 + (0 * 16 + ks) * 64 + aL] = g0;
      red[2048 + (1 * 16 + ks) * 64 + aL] = g1;
    }
    // xw prefetch (both batches)
    if (t < 256) {
      xwv0 = (float)xw16[(((size_t)(b0 * 8 + oct)) * 256 + step) * 256 + t];
      xwv1 = (float)xw16[(((size_t)(b1 * 8 + oct)) * 256 + step) * 256 + t];
    }
    __syncthreads();
    // reduces: hU -> pre (as accumulator), hatt -> hattL
    if (t < 512) {
      int bq = t >> 8, cc2 = t & 255;
      pre[bq * 256 + cc2] = red[(bq * 4 + 0) * 256 + cc2] +
                            red[(bq * 4 + 1) * 256 + cc2] +
                            red[(bq * 4 + 2) * 256 + cc2] +
                            red[(bq * 4 + 3) * 256 + cc2];
    } else if (t < 640) {
      int r = t - 512, bq = r >> 6, a = r & 63;
      float s = 0.f;
#pragma unroll
      for (int k = 0; k < 16; k++) s += red[2048 + (bq * 16 + k) * 64 + a];
      hattL[r] = s;
    }
    __syncthreads();
    // score partials (my 64 a-cols), both batches
    {
      const int l = t >> 3, as = t & 7;
#pragma unroll
      for (int bq = 0; bq < 2; bq++) {
        const h16* arow = attcL + (size_t)(bq * 128 + l) * 66 + 8 * as;
        const float* hb_ = hattL + bq * 64 + 8 * as;
        float p = 0.f;
#pragma unroll
        for (int aa = 0; aa < 8; aa++)
          p += ftanh((float)arow[aa] + hb_[aa]) * wpL[8 * as + aa];
        p += __shfl_xor(p, 1); p += __shfl_xor(p, 2); p += __shfl_xor(p, 4);
        if (as == 0)
          cstoref(scP + (((size_t)par * 32 + b0 + bq) * 8 + oct) * 128 + l, p);
      }
    }
    __syncthreads();                    // drain score stores (release)
    if (t == 0) cstorei(scFmine, step + 1);

    // ---- Phase B ----
    pollgrp(scF, step + 1);
#pragma unroll
    for (int bq = 0; bq < 2; bq++)
      spp[bq * 1024 + t] =
          cloadf(scP + (((size_t)par * 32 + b0 + bq) * 8) * 128 + t);
    __syncthreads();
    if (t < 128) {  // softmax, one wave per batch
      int bq = t >> 6, lane = t & 63;
      float s0 = 0.f, s1 = 0.f;
#pragma unroll
      for (int o = 0; o < 8; o++) {
        s0 += spp[bq * 1024 + o * 128 + lane];
        s1 += spp[bq * 1024 + o * 128 + 64 + lane];
      }
      float e0 = __expf(s0), e1 = __expf(s1);
      sl[bq * 128 + lane] = e0; sl[bq * 128 + 64 + lane] = e1;
      float z = e0 + e1;
      z += __shfl_xor(z, 32); z += __shfl_xor(z, 16); z += __shfl_xor(z, 8);
      z += __shfl_xor(z, 4);  z += __shfl_xor(z, 2);  z += __shfl_xor(z, 1);
      float zi = rcp_fast(z);
      anL[bq * 64 + lane] = h2{(h16)(sl[bq * 128 + 2 * lane] * zi),
                               (h16)(sl[bq * 128 + 2 * lane + 1] * zi)};
    }
    __syncthreads();
    // PV b0
    {
      const int w16 = t >> 6;
      h2 a01 = anL[2 * lq], a23 = anL[2 * lq + 1];
      float acc8[8];
#pragma unroll
      for (int j8 = 0; j8 < 8; j8++)
        acc8[j8] = fdot2(a23, cvA23[j8], fdot2(a01, cvA01[j8], 0.f));
#pragma unroll
      for (int j8 = 0; j8 < 8; j8++) acc8[j8] += __shfl_xor(acc8[j8], 32);
      if ((t & 63) < 32) {
#pragma unroll
        for (int j8 = 0; j8 < 8; j8++) red[w16 * 256 + ccg * 8 + j8] = acc8[j8];
      }
    }
    __syncthreads();
    if (t < 256) {
      float pvs = 0.f;
#pragma unroll
      for (int k = 0; k < 16; k++) pvs += red[k * 256 + t];
      pre[t] = pvs + pre[t] + xwv0 + biasS[t];
    }
    __syncthreads();
    // PV b1
    {
      const int w16 = t >> 6;
      h2 a01 = anL[64 + 2 * lq], a23 = anL[64 + 2 * lq + 1];
      float acc8[8];
#pragma unroll
      for (int j8 = 0; j8 < 8; j8++)
        acc8[j8] = fdot2(a23, cvB23[j8], fdot2(a01, cvB01[j8], 0.f));
#pragma unroll
      for (int j8 = 0; j8 < 8; j8++) acc8[j8] += __shfl_xor(acc8[j8], 32);
      if ((t & 63) < 32) {
#pragma unroll
        for (int j8 = 0; j8 < 8; j8++) red[w16 * 256 + ccg * 8 + j8] = acc8[j8];
      }
    }
    __syncthreads();
    if (t < 256) {
      float pvs = 0.f;
#pragma unroll
      for (int k = 0; k < 16; k++) pvs += red[k * 256 + t];
      pre[256 + t] = pvs + pre[256 + t] + xwv1 + biasS[t];
    }
    __syncthreads();
    // gates: t<128 covers both batches (64 dims each)
    if (t < 128) {
      int bq = t >> 6, d = t & 63;
      float pi = pre[bq * 256 + d],       pf = pre[bq * 256 + 64 + d];
      float po = pre[bq * 256 + 128 + d], pg = pre[bq * 256 + 192 + d];
      float ig = fsig(pi), fg = fsig(pf), og = fsig(po), gg = ftanh(pg);
      float cn = fg * c_reg + ig * gg;
      c_reg = cn;
      float hn = og * ftanh(cn);
      hn_prev = hn;
      cstores(hX + ((size_t)par * 32 + b0 + bq) * DD + 64 * oct + d, (h16)hn);
    }
    __syncthreads();                    // drain h stores (release)
    if (t == 0) cstorei(hFmine, step + 1);
  }
  // final out stores
  if (t < 128) {
    int bq = t >> 6, d = t & 63;
    out[((size_t)(b0 + bq) * TSTEPS + TSTEPS - 1) * DD + 64 * oct + d] = hn_prev;
  }
}

extern "C" void kernel_launch(void* const* d_in, const int* in_sizes, int n_in,
                              void* d_out, int out_size, void* d_ws, size_t ws_size,
                              hipStream_t stream) {
  (void)in_sizes; (void)n_in; (void)out_size; (void)ws_size;
  const float* x    = (const float*)d_in[0];
  const float* ctx  = (const float*)d_in[1];
  const float* W    = (const float*)d_in[2];
  const float* V    = (const float*)d_in[3];
  const float* U    = (const float*)d_in[4];
  const float* b    = (const float*)d_in[5];
  const float* Wh   = (const float*)d_in[6];
  const float* Wc   = (const float*)d_in[7];
  const float* batt = (const float*)d_in[8];
  const float* wprj = (const float*)d_in[9];

  // zero grid flags + rel + sc/h flags
  hipMemsetAsync(d_ws, 0, (8192 + 256 + 8192) * sizeof(int), stream);

  hipLaunchKernelGGL(attn_lstm_persistent, dim3(GD), dim3(BD), 0, stream,
                     x, ctx, W, V, U, b, Wh, Wc, batt, wprj,
                     (float*)d_out, (float*)d_ws);
}

// Round 12
// 2428.528 us; speedup vs baseline: 4.0787x; 4.0787x over previous
//
#include <hip/hip_runtime.h>
#include <hip/hip_fp16.h>

#define GD 256   // 1 WG per CU, persistent
#define BD 1024  // 16 waves

constexpr int TSTEPS = 256;
constexpr int DD = 512;
constexpr int LC = 128;

// ---- ws float offsets ----
constexpr size_t OFF_FLAGS_F = 0;       // grid flags: 256 lines (stride 32 ints)
constexpr size_t OFF_REL_F   = 8192;    // 8 release lines
constexpr size_t OFF_GFLG_F  = 8448;    // group flags [8 xg][32 j][32 ints]
constexpr size_t OFF_HUX     = 16640;   // [32 b][2048 gcol] f32 hU exchange
constexpr size_t OFF_SCP     = 82176;   // [32 b][32 j][128 l] f32 score partials
constexpr size_t OFF_H16_F   = 213248;  // h16 base
// ---- h16-unit offsets ----
constexpr size_t HO_HX    = 0;          // [32 b][512] h (latest only)
constexpr size_t HO_ATT   = 16384;      // [4096 r][512] attc
constexpr size_t HO_U16   = 2113536;    // [8 oct][256 kp][256 cc] h2
constexpr size_t HO_WH16  = 3162112;    // [8 octa][256 kp][64 a] h2
constexpr size_t HO_CTXV  = 3424256;    // [32 b][8 oct][128 l][256 cc]
constexpr size_t HO_XW    = 11812864;   // [32 b][8 oct][256 st][256 cc]

typedef _Float16 h16;
typedef _Float16 h2  __attribute__((ext_vector_type(2)));
typedef _Float16 h8v __attribute__((ext_vector_type(8)));
union H8  { h8v v; h2 p[4]; };
union H2U { h2 h; unsigned u; };
union HSU { h16 h; unsigned short u; };

__device__ __forceinline__ float rcp_fast(float x) { return __builtin_amdgcn_rcpf(x); }
__device__ __forceinline__ float ftanh(float x) {
  float e = __expf(2.0f * x);
  return 1.0f - 2.0f * rcp_fast(e + 1.0f);
}
__device__ __forceinline__ float fsig(float x) { return rcp_fast(1.0f + __expf(-x)); }
__device__ __forceinline__ float fdot2(h2 a, h2 b, float c) {
  return __builtin_amdgcn_fdot2(a, b, c, false);
}

__device__ __forceinline__ float cloadf(const float* p) {
  return __hip_atomic_load(p, __ATOMIC_RELAXED, __HIP_MEMORY_SCOPE_AGENT);
}
__device__ __forceinline__ unsigned cloadu(const unsigned* p) {
  return __hip_atomic_load(p, __ATOMIC_RELAXED, __HIP_MEMORY_SCOPE_AGENT);
}
__device__ __forceinline__ void cstoref(float* p, float v) {
  __hip_atomic_store(p, v, __ATOMIC_RELAXED, __HIP_MEMORY_SCOPE_AGENT);
}
__device__ __forceinline__ void cstoreu(unsigned* p, unsigned v) {
  __hip_atomic_store(p, v, __ATOMIC_RELAXED, __HIP_MEMORY_SCOPE_AGENT);
}
__device__ __forceinline__ void cstoreu8(unsigned long long* p, unsigned long long v) {
  __hip_atomic_store(p, v, __ATOMIC_RELAXED, __HIP_MEMORY_SCOPE_AGENT);
}
__device__ __forceinline__ void cstores(h16* p, h16 v) {
  HSU s; s.h = v;
  __hip_atomic_store((unsigned short*)p, s.u, __ATOMIC_RELAXED,
                     __HIP_MEMORY_SCOPE_AGENT);
}

// grid barrier (setup only)
__device__ __forceinline__ void gsync(int* flags, int* rel, int w, int& gen) {
  __syncthreads();
  gen++;
  const int t = threadIdx.x;
  if (w == 0) {
    if (t < 64) {
      if (t == 0)
        __hip_atomic_store(flags, gen, __ATOMIC_RELAXED, __HIP_MEMORY_SCOPE_AGENT);
      for (;;) {
        int m = gen;
#pragma unroll
        for (int i = 0; i < 4; i++) {
          int v = __hip_atomic_load(flags + (t + i * 64) * 32,
                                    __ATOMIC_RELAXED, __HIP_MEMORY_SCOPE_AGENT);
          m = (v < m) ? v : m;
        }
        if (__all(m >= gen)) break;
      }
      if (t == 0) {
#pragma unroll
        for (int i = 0; i < 8; i++)
          __hip_atomic_store(rel + i * 32, gen, __ATOMIC_RELAXED,
                             __HIP_MEMORY_SCOPE_AGENT);
      }
    }
    asm volatile("" ::: "memory");
  } else {
    if (t == 0) {
      __hip_atomic_store(flags + w * 32, gen, __ATOMIC_RELAXED,
                         __HIP_MEMORY_SCOPE_AGENT);
      const int* r = rel + (w & 7) * 32;
      while (__hip_atomic_load(r, __ATOMIC_RELAXED, __HIP_MEMORY_SCOPE_AGENT) < gen)
        __builtin_amdgcn_s_sleep(1);
    }
    asm volatile("" ::: "memory");
  }
  __syncthreads();
}

// 32-WG group barrier: symmetric flag + poll
__device__ __forceinline__ void gbar32(int* gf, int j, int& sg) {
  __syncthreads();
  sg++;
  const int t = threadIdx.x;
  if (t < 64) {
    if (t == 0)
      __hip_atomic_store(gf + j * 32, sg, __ATOMIC_RELAXED,
                         __HIP_MEMORY_SCOPE_AGENT);
    for (;;) {
      int v = sg;
      if (t < 32)
        v = __hip_atomic_load(gf + t * 32, __ATOMIC_RELAXED,
                              __HIP_MEMORY_SCOPE_AGENT);
      if (__all(v >= sg)) break;
      __builtin_amdgcn_s_sleep(1);
    }
  }
  asm volatile("" ::: "memory");
  __syncthreads();
}

__global__ __launch_bounds__(BD, 4) void attn_lstm_persistent(
    const float* __restrict__ x, const float* __restrict__ ctx,
    const float* __restrict__ W, const float* __restrict__ V,
    const float* __restrict__ U, const float* __restrict__ bias,
    const float* __restrict__ Wh, const float* __restrict__ Wc,
    const float* __restrict__ batt, const float* __restrict__ wprj,
    float* __restrict__ out, float* __restrict__ ws) {
  __shared__ __align__(16) unsigned char smem[58448];
  h16*   attcL = (h16*)smem;                   // [512 row][18] (pad-18 banks)
  float* red   = (float*)(smem + 18432);       // 4096 f32
  float* red2  = (float*)(smem + 34816);       // 4096 f32
  h2*    hLDS  = (h2*)(smem + 51200);          // [4 q][256 kp]
  float* sl    = (float*)(smem + 55296);       // 128
  h2*    anL   = (h2*)(smem + 55808);          // 64 (fp16 alpha pairs)
  float* hattL = (float*)(smem + 56064);       // 64  ([q][16 a])
  float* wpL   = (float*)(smem + 56320);       // 16
  float* biasS = (float*)(smem + 56384);       // 256
  float* pre   = (float*)(smem + 57408);       // 256

  const int w = blockIdx.x;
  const int t = threadIdx.x;
  // recurrence roles: group = same (blockIdx % 8)
  const int xg = w & 7;        // group id, batches [4xg, 4xg+4)
  const int j  = w >> 3;       // member 0..31: owns gcols [64j,64j+64), a [16j,16j+16)
  const int q2 = j >> 3;       // P2 batch-in-group
  const int bb = 4 * xg + q2;  // P2 batch
  const int oct = j & 7;       // P2 out-dims [64oct, 64oct+64)

  int* flags = (int*)(ws + OFF_FLAGS_F);
  int* rel   = (int*)(ws + OFF_REL_F);
  int* gfl   = (int*)(ws + OFF_GFLG_F) + xg * 1024;
  float* hUX = ws + OFF_HUX;
  float* scP = ws + OFF_SCP;
  h16* hb16  = (h16*)(ws + OFF_H16_F);
  h16* hX    = hb16 + HO_HX;
  h16* att16 = hb16 + HO_ATT;
  h16* ctxVp = hb16 + HO_CTXV;
  h16* xw16  = hb16 + HO_XW;

  int gen = 0, sg = 0;
  float c_reg = 0.f;           // t<64: c[bb][64oct + t]
  float hn_prev = 0.f;         // t<64: deferred out-store value

  // ================= setup (verified packing, kept identical) =================
  {
    const int kp = w;
    {
      const float* r0p = U + (size_t)(2 * kp) * 2048;
      const float* r1p = r0p + 2048;
      const int col0 = 2 * t;
      float u00 = r0p[col0], u01 = r0p[col0 + 1];
      float u10 = r1p[col0], u11 = r1p[col0 + 1];
      int oc  = (col0 & 511) >> 6;
      int cc0 = ((col0 >> 9) << 6) | (col0 & 63);
      H2U p0; p0.h = h2{(h16)u00, (h16)u10};
      H2U p1; p1.h = h2{(h16)u01, (h16)u11};
      unsigned long long pk =
          (unsigned long long)p0.u | ((unsigned long long)p1.u << 32);
      cstoreu8((unsigned long long*)((h2*)(hb16 + HO_U16) +
                                     (size_t)oc * 65536 + (size_t)kp * 256 + cc0),
               pk);
    }
    if (t < 512) {
      float w0 = Wh[(size_t)(2 * kp) * DD + t];
      float w1 = Wh[(size_t)(2 * kp + 1) * DD + t];
      H2U pu; pu.h = h2{(h16)w0, (h16)w1};
      cstoreu((unsigned*)((h2*)(hb16 + HO_WH16) + (size_t)(t >> 6) * 16384 +
                          (size_t)kp * 64 + (t & 63)),
              pu.u);
    }
  }
  // attc16 = fp16(ctx @ Wc + b_att): 16 rows per WG
  {
    float* fbuf = (float*)smem;  // 32 KB staging (dead after gsync)
    const int r0 = w * 16;
#pragma unroll
    for (int i = 0; i < 2; i++) {
      int idx4 = i * BD + t;
      int row = idx4 >> 7, c4 = idx4 & 127;
      ((float4*)fbuf)[idx4] = ((const float4*)(ctx + (size_t)(r0 + row) * DD))[c4];
    }
    __syncthreads();
    const int a0 = t & 511, rh = t >> 9;
    float acc[8];
#pragma unroll
    for (int r = 0; r < 8; r++) acc[r] = 0.f;
    for (int cc = 0; cc < DD; cc++) {
      float wv = Wc[(size_t)cc * DD + a0];
#pragma unroll
      for (int r = 0; r < 8; r++)
        acc[r] += fbuf[(8 * rh + r) * DD + cc] * wv;
    }
    const float ba = batt[a0];
    for (int r = 0; r < 8; r++)
      cstores(att16 + (size_t)(r0 + 8 * rh + r) * DD + a0, (h16)(acc[r] + ba));
    __syncthreads();
  }
  // xw16 / ctxVp produced with setup-role (bS, octS) — layouts unchanged
  {
    const int bS = w >> 3, octS = w & 7;
    h2* xstage = (h2*)smem;  // [32][256]
    for (int chk = 0; chk < 8; chk++) {
      const int st0 = chk * 32;
      {
        const int row = t >> 5, seg = t & 31;
        const float* src = x + ((size_t)bS * TSTEPS + st0 + row) * DD + seg * 16;
        h2* dst = xstage + row * 256 + seg * 8;
#pragma unroll
        for (int q = 0; q < 4; q++) {
          float4 v = *(const float4*)(src + 4 * q);
          dst[2 * q]     = h2{(h16)v.x, (h16)v.y};
          dst[2 * q + 1] = h2{(h16)v.z, (h16)v.w};
        }
      }
      __syncthreads();
      const int cc = t & 255, sq = t >> 8;
      const int col = ((cc >> 6) << 9) + 64 * octS + (cc & 63);
      float acc[8];
#pragma unroll
      for (int jj = 0; jj < 8; jj++) acc[jj] = 0.f;
#pragma unroll 2
      for (int kp = 0; kp < 256; kp++) {
        float w0 = W[(size_t)(2 * kp) * 2048 + col];
        float w1 = W[(size_t)(2 * kp + 1) * 2048 + col];
        h2 wp = h2{(h16)w0, (h16)w1};
#pragma unroll
        for (int jj = 0; jj < 8; jj++)
          acc[jj] = fdot2(xstage[(sq * 8 + jj) * 256 + kp], wp, acc[jj]);
      }
#pragma unroll
      for (int jj = 0; jj < 8; jj++)
        cstores(xw16 + (((size_t)(bS * 8 + octS) * 256) + st0 + sq * 8 + jj) * 256 + cc,
                (h16)acc[jj]);
      __syncthreads();
    }
    for (int chk = 0; chk < 4; chk++) {
      const int l0 = chk * 32;
      {
        const int row = t >> 5, seg = t & 31;
        const float* src = ctx + ((size_t)bS * LC + l0 + row) * DD + seg * 16;
        h2* dst = xstage + row * 256 + seg * 8;
#pragma unroll
        for (int q = 0; q < 4; q++) {
          float4 v = *(const float4*)(src + 4 * q);
          dst[2 * q]     = h2{(h16)v.x, (h16)v.y};
          dst[2 * q + 1] = h2{(h16)v.z, (h16)v.w};
        }
      }
      __syncthreads();
      const int cc = t & 255, lq2 = t >> 8;
      const int col = ((cc >> 6) << 9) + 64 * octS + (cc & 63);
      float acc[8];
#pragma unroll
      for (int jj = 0; jj < 8; jj++) acc[jj] = 0.f;
#pragma unroll 2
      for (int kp = 0; kp < 256; kp++) {
        float v0 = V[(size_t)(2 * kp) * 2048 + col];
        float v1 = V[(size_t)(2 * kp + 1) * 2048 + col];
        h2 vp = h2{(h16)v0, (h16)v1};
#pragma unroll
        for (int jj = 0; jj < 8; jj++)
          acc[jj] = fdot2(xstage[(lq2 * 8 + jj) * 256 + kp], vp, acc[jj]);
      }
#pragma unroll
      for (int jj = 0; jj < 8; jj++)
        cstores(ctxVp + (((size_t)(bS * 8 + octS) * 128) + l0 + lq2 * 8 + jj) * 256 + cc,
                (h16)acc[jj]);
      __syncthreads();
    }
  }
  gsync(flags, rel, w, gen);

  // ======== load persistent operands: U->16 VGPR, Wh->4, ctxV->16, attc->LDS ====
  const int ccL = t & 63, kseg = t >> 6;   // hU: col 64j+ccL, kp in [16kseg,+16)
  const int aL = t & 15, ks2 = t >> 4;     // hatt: a 16j+aL, kp in [4ks2,+4)
  h2 u[16], wh[4], cvp01[8], cvp23[8];
  {
    const h2* Ub = (const h2*)(hb16 + HO_U16) + (size_t)(j & 7) * 65536 +
                   (size_t)(j >> 3) * 64 + ccL;
#pragma unroll
    for (int i = 0; i < 16; i++) u[i] = Ub[(size_t)(16 * kseg + i) * 256];
    const h2* Wb = (const h2*)(hb16 + HO_WH16) + (size_t)(j >> 2) * 16384 +
                   16 * (j & 3) + aL;
#pragma unroll
    for (int i = 0; i < 4; i++) wh[i] = Wb[(size_t)(4 * ks2 + i) * 64];
  }
  {
    const int ccg = t & 31, lq = t >> 5;
    const h16* cvb = ctxVp + ((size_t)(bb * 8 + oct) * 128) * 256 + ccg * 8;
    H8 p0, p1, p2, p3;
    p0.v = *(const h8v*)(cvb + (size_t)(4 * lq + 0) * 256);
    p1.v = *(const h8v*)(cvb + (size_t)(4 * lq + 1) * 256);
    p2.v = *(const h8v*)(cvb + (size_t)(4 * lq + 2) * 256);
    p3.v = *(const h8v*)(cvb + (size_t)(4 * lq + 3) * 256);
#pragma unroll
    for (int j8 = 0; j8 < 8; j8++) {
      cvp01[j8] = h2{p0.v[j8], p1.v[j8]};
      cvp23[j8] = h2{p2.v[j8], p3.v[j8]};
    }
  }
  {
    // attcL[row=q*128+l][18]: my 16 a-cols for 4 batches
    const int row = t >> 1, half = t & 1, q = row >> 7, l = row & 127;
    uint4 v = *(const uint4*)(att16 + (size_t)((4 * xg + q) * LC + l) * DD +
                              16 * j + 8 * half);
    unsigned* dp = (unsigned*)(attcL + row * 18 + 8 * half);
    dp[0] = v.x; dp[1] = v.y; dp[2] = v.z; dp[3] = v.w;
  }
  if (t < 16) wpL[t] = wprj[16 * j + t];
  if (t < 256) biasS[t] = bias[(size_t)(t >> 6) * 512 + 64 * oct + (t & 63)];
  __syncthreads();

  // ========== recurrence: 2 phases, 2 group barriers/step ==========
  for (int step = 0; step < TSTEPS; step++) {
    float xwv = 0.f;

    // deferred out-store for previous step (ack drains under P1 compute)
    if (t < 64 && step > 0)
      out[((size_t)bb * TSTEPS + step - 1) * DD + 64 * oct + t] = hn_prev;

    // ---- P1: h gather; hU (regs) + hatt (regs) partials; scores (my 16 a) ----
    {
      unsigned hv = 0;
      if (step > 0)
        hv = cloadu((const unsigned*)(hX + (size_t)(4 * xg + (t >> 8)) * DD +
                                      2 * (t & 255)));
      ((unsigned*)hLDS)[t] = hv;
      __syncthreads();
      // hU partials: 4 batches x 16 fdot2
      {
        float f0 = 0.f, f1 = 0.f, f2 = 0.f, f3 = 0.f;
        const int base = 16 * kseg;
#pragma unroll
        for (int i = 0; i < 16; i++) {
          h2 uu = u[i];
          f0 = fdot2(hLDS[base + i], uu, f0);
          f1 = fdot2(hLDS[256 + base + i], uu, f1);
          f2 = fdot2(hLDS[512 + base + i], uu, f2);
          f3 = fdot2(hLDS[768 + base + i], uu, f3);
        }
        red[kseg * 256 + ccL]       = f0;
        red[kseg * 256 + 64 + ccL]  = f1;
        red[kseg * 256 + 128 + ccL] = f2;
        red[kseg * 256 + 192 + ccL] = f3;
      }
      // hatt partials: 4 batches x 4 fdot2
      {
        float g0 = 0.f, g1 = 0.f, g2 = 0.f, g3 = 0.f;
        const int base = 4 * ks2;
#pragma unroll
        for (int i = 0; i < 4; i++) {
          h2 ww = wh[i];
          g0 = fdot2(hLDS[base + i], ww, g0);
          g1 = fdot2(hLDS[256 + base + i], ww, g1);
          g2 = fdot2(hLDS[512 + base + i], ww, g2);
          g3 = fdot2(hLDS[768 + base + i], ww, g3);
        }
        red2[ks2 * 64 + aL]      = g0;
        red2[ks2 * 64 + 16 + aL] = g1;
        red2[ks2 * 64 + 32 + aL] = g2;
        red2[ks2 * 64 + 48 + aL] = g3;
      }
      // xw prefetch for this step (overlaps partial compute + barrier wait)
      if (t < 256)
        xwv = (float)xw16[(((size_t)(bb * 8 + oct)) * 256 + step) * 256 + t];
      __syncthreads();
      if (t < 256) {  // hU reduce + publish (gcol = 64j + cc)
        float s = 0.f;
#pragma unroll
        for (int k = 0; k < 16; k++) s += red[k * 256 + t];
        cstoref(hUX + (size_t)(4 * xg + (t >> 6)) * 2048 + 64 * j + (t & 63), s);
      } else if (t < 320) {  // hatt reduce -> hattL[q*16+aL]
        const int r = t - 256;
        float s = 0.f;
#pragma unroll
        for (int k = 0; k < 64; k++) s += red2[k * 64 + r];
        hattL[r] = s;
      }
      __syncthreads();
      // score partials over my 16 a, all 4 batches x 128 l
      {
        const int row = t >> 1, half = t & 1, q = row >> 7;
        const h16* arow = attcL + row * 18 + 8 * half;
        const float* hb_ = hattL + q * 16 + 8 * half;
        const float* wp_ = wpL + 8 * half;
        float p = 0.f;
#pragma unroll
        for (int aa = 0; aa < 8; aa++)
          p += ftanh((float)arow[aa] + hb_[aa]) * wp_[aa];
        p += __shfl_xor(p, 1);
        if (half == 0)
          cstoref(scP + (size_t)(4 * xg + q) * 4096 + j * 128 + (row & 127), p);
      }
    }
    gbar32(gfl, j, sg);

    // ---- P2: sum 32 partials -> 1-wave softmax -> PV(fdot2 regs) -> gates ----
    {
      float hUv = 0.f;
      if (t < 256)
        hUv = cloadf(hUX + (size_t)bb * 2048 + (size_t)(t >> 6) * 512 +
                     64 * oct + (t & 63));
#pragma unroll
      for (int r = 0; r < 4; r++)
        red[r * 1024 + t] = cloadf(scP + (size_t)bb * 4096 + r * 1024 + t);
      __syncthreads();
      if (t < 64) {  // single-wave softmax: sums, exp, z, fp16 alphas
        float s0 = 0.f, s1 = 0.f;
#pragma unroll
        for (int jj = 0; jj < 32; jj++) {
          s0 += red[jj * 128 + t];
          s1 += red[jj * 128 + 64 + t];
        }
        float e0 = __expf(s0), e1 = __expf(s1);
        sl[t] = e0; sl[64 + t] = e1;
        float z = e0 + e1;
        z += __shfl_xor(z, 32); z += __shfl_xor(z, 16); z += __shfl_xor(z, 8);
        z += __shfl_xor(z, 4);  z += __shfl_xor(z, 2);  z += __shfl_xor(z, 1);
        float zi = rcp_fast(z);
        anL[t] = h2{(h16)(sl[2 * t] * zi), (h16)(sl[2 * t + 1] * zi)};
      }
      __syncthreads();
      {
        const int ccg = t & 31, lq = t >> 5, w16 = t >> 6;
        h2 a01 = anL[2 * lq], a23 = anL[2 * lq + 1];
        float acc8[8];
#pragma unroll
        for (int j8 = 0; j8 < 8; j8++)
          acc8[j8] = fdot2(a23, cvp23[j8], fdot2(a01, cvp01[j8], 0.f));
#pragma unroll
        for (int j8 = 0; j8 < 8; j8++) acc8[j8] += __shfl_xor(acc8[j8], 32);
        if ((t & 63) < 32) {
#pragma unroll
          for (int j8 = 0; j8 < 8; j8++)
            red[w16 * 256 + ccg * 8 + j8] = acc8[j8];
        }
      }
      __syncthreads();
      if (t < 256) {
        float pvs = 0.f;
#pragma unroll
        for (int k = 0; k < 16; k++) pvs += red[k * 256 + t];
        pre[t] = pvs + hUv + xwv + biasS[t];  // pvs already normalized
      }
      __syncthreads();
      if (t < 64) {
        const int d = t;
        float pi = pre[d], pf = pre[64 + d], po = pre[128 + d], pg = pre[192 + d];
        float ig = fsig(pi), fg = fsig(pf), og = fsig(po), gg = ftanh(pg);
        float cn = fg * c_reg + ig * gg;
        c_reg = cn;
        float hn = og * ftanh(cn);
        hn_prev = hn;
        cstores(hX + (size_t)bb * DD + 64 * oct + d, (h16)hn);
      }
    }
    gbar32(gfl, j, sg);
  }
  // final out-store (step TSTEPS-1)
  if (t < 64)
    out[((size_t)bb * TSTEPS + TSTEPS - 1) * DD + 64 * oct + t] = hn_prev;
}

extern "C" void kernel_launch(void* const* d_in, const int* in_sizes, int n_in,
                              void* d_out, int out_size, void* d_ws, size_t ws_size,
                              hipStream_t stream) {
  (void)in_sizes; (void)n_in; (void)out_size; (void)ws_size;
  const float* x    = (const float*)d_in[0];
  const float* ctx  = (const float*)d_in[1];
  const float* W    = (const float*)d_in[2];
  const float* V    = (const float*)d_in[3];
  const float* U    = (const float*)d_in[4];
  const float* b    = (const float*)d_in[5];
  const float* Wh   = (const float*)d_in[6];
  const float* Wc   = (const float*)d_in[7];
  const float* batt = (const float*)d_in[8];
  const float* wprj = (const float*)d_in[9];

  // zero grid flags + rel + group flags
  hipMemsetAsync(d_ws, 0, (8192 + 256 + 8192) * sizeof(int), stream);

  hipLaunchKernelGGL(attn_lstm_persistent, dim3(GD), dim3(BD), 0, stream,
                     x, ctx, W, V, U, b, Wh, Wc, batt, wprj,
                     (float*)d_out, (float*)d_ws);
}